// Round 4
// baseline (751.047 us; speedup 1.0000x reference)
//
#include <hip/hip_runtime.h>

typedef float v2f __attribute__((ext_vector_type(2)));
typedef float v4f __attribute__((ext_vector_type(4)));

#define QN 16384
#define SN 16384
#define HN 32
#define EN 393216
#define KPAD 68   // 17*16B rows: float4-aligned, measured 0 bank conflicts

// ---------------- per-question tables ----------------
// xKpos/xKneg = x@W_K + b_K + h1_bias[ch]
// xVf  = (x@W_V + b_V) @ W_fuse[64:128]
// xQ1  = x@W_Q[0:64]
// xq2  = x @ W_K2^T
// c2{pos,neg}[q] = scale * sum_f x[q][f]*(b_K2[f] + h2_bias[ch][f])
__global__ __launch_bounds__(256) void p1_kernel(
    const float* __restrict__ x,
    const float* __restrict__ W_K, const float* __restrict__ b_K,
    const float* __restrict__ W_V, const float* __restrict__ b_V,
    const float* __restrict__ W_Q,
    const float* __restrict__ W_K2, const float* __restrict__ b_K2,
    const float* __restrict__ W_fuse,
    const float* __restrict__ h1b, const float* __restrict__ h2b,
    float* __restrict__ xKpos, float* __restrict__ xKneg,
    float* __restrict__ xVf, float* __restrict__ xQ1, float* __restrict__ xq2,
    float* __restrict__ c2pos, float* __restrict__ c2neg)
{
  __shared__ float xs[8 * 64];
  __shared__ float vs[8 * 64];
  __shared__ float wk2t[64 * 66];   // transposed W_K2, padded
  int t = threadIdx.x;
  int j = t & 31, r = t >> 5;
  int q = blockIdx.x * 8 + r;
  if (t < 128) *(v4f*)&xs[t * 4] = *(const v4f*)&x[blockIdx.x * 512 + t * 4];
  for (int i = 0; i < 16; i++) {
    int idx = i * 256 + t;
    wk2t[(idx & 63) * 66 + (idx >> 6)] = W_K2[idx];   // wk2t[b][a] = W_K2[a][b]
  }
  __syncthreads();

  v2f accK = *(const v2f*)&b_K[2 * j];
  v2f accV = *(const v2f*)&b_V[2 * j];
  v2f accQ = {0.f, 0.f};
  v2f acc2 = {0.f, 0.f};
  for (int g = 0; g < 64; g++) {
    float xv = xs[r * 64 + g];
    accK += xv * *(const v2f*)&W_K[g * 64 + 2 * j];
    accV += xv * *(const v2f*)&W_V[g * 64 + 2 * j];
    accQ += xv * *(const v2f*)&W_Q[g * 64 + 2 * j];
    acc2 += xv * *(const v2f*)&wk2t[g * 66 + 2 * j];  // = W_K2[f][g]
  }
  *(v2f*)&xKpos[q * 64 + 2 * j] = accK + *(const v2f*)&h1b[2 * j];
  *(v2f*)&xKneg[q * 64 + 2 * j] = accK + *(const v2f*)&h1b[64 + 2 * j];
  *(v2f*)&xQ1[q * 64 + 2 * j] = accQ;
  *(v2f*)&xq2[q * 64 + 2 * j] = acc2;
  *(v2f*)&vs[r * 64 + 2 * j] = accV;

  v2f xv2 = *(const v2f*)&xs[r * 64 + 2 * j];
  v2f bb0 = *(const v2f*)&b_K2[2 * j] + *(const v2f*)&h2b[2 * j];
  v2f bb1 = *(const v2f*)&b_K2[2 * j] + *(const v2f*)&h2b[64 + 2 * j];
  v2f t0 = xv2 * bb0, t1 = xv2 * bb1;
  float p0 = t0.x + t0.y, p1 = t1.x + t1.y;
  for (int k = 16; k >= 1; k >>= 1) {
    p0 += __shfl_xor(p0, k, 32);
    p1 += __shfl_xor(p1, k, 32);
  }
  if (j == 0) { c2pos[q] = p0 * 0.125f; c2neg[q] = p1 * 0.125f; }

  __syncthreads();
  v2f aVf = {0.f, 0.f};
  for (int g = 0; g < 64; g++)
    aVf += vs[r * 64 + g] * *(const v2f*)&W_fuse[(64 + g) * 64 + 2 * j];
  *(v2f*)&xVf[q * 64 + 2 * j] = aVf;
}

// ---------------- per-student tables ----------------
__global__ __launch_bounds__(256) void p2_kernel(
    const float* __restrict__ s_emb,
    const float* __restrict__ W_Q, const float* __restrict__ b_Q,
    const float* __restrict__ W_fuse, const float* __restrict__ b_fuse,
    float* __restrict__ sQ, float* __restrict__ sf)
{
  __shared__ float xs[8 * 64];
  int t = threadIdx.x;
  int j = t & 31, r = t >> 5;
  int s = blockIdx.x * 8 + r;
  if (t < 128) *(v4f*)&xs[t * 4] = *(const v4f*)&s_emb[blockIdx.x * 512 + t * 4];
  __syncthreads();
  v2f aq = *(const v2f*)&b_Q[2 * j];
  v2f af = *(const v2f*)&b_fuse[2 * j];
  for (int g = 0; g < 64; g++) {
    float v = xs[r * 64 + g];
    aq += v * *(const v2f*)&W_Q[(64 + g) * 64 + 2 * j];
    af += v * *(const v2f*)&W_fuse[g * 64 + 2 * j];
  }
  *(v2f*)&sQ[s * 64 + 2 * j] = aq;
  *(v2f*)&sf[s * 64 + 2 * j] = af;
}

// ---------------- CSR build ----------------
__global__ __launch_bounds__(256) void hist_kernel(
    const int* __restrict__ sid_pos, const int* __restrict__ sid_neg,
    int* __restrict__ cnt_pos, int* __restrict__ cnt_neg, int n) {
  const int* sid = blockIdx.y ? sid_neg : sid_pos;
  int* cnt = blockIdx.y ? cnt_neg : cnt_pos;
  int i = blockIdx.x * 256 + threadIdx.x;
  if (i < n) atomicAdd(&cnt[sid[i]], 1);
}

// Coalesced permuted scan: ranges need only be disjoint, not ordered by s.
// Thread t owns students {t, t+256, ..., t+63*256}.
__global__ __launch_bounds__(256) void scan_kernel(
    const int* __restrict__ cnt_pos, int* __restrict__ beg_pos, int* __restrict__ cur_pos,
    const int* __restrict__ cnt_neg, int* __restrict__ beg_neg, int* __restrict__ cur_neg) {
  const int* cnt = blockIdx.y ? cnt_neg : cnt_pos;
  int* beg = blockIdx.y ? beg_neg : beg_pos;
  int* cur = blockIdx.y ? cur_neg : cur_pos;
  __shared__ int part[256];
  int t = threadIdx.x;
  int s = 0;
  for (int i = 0; i < 64; i++) s += cnt[i * 256 + t];   // coalesced
  part[t] = s;
  __syncthreads();
  for (int off = 1; off < 256; off <<= 1) {
    int v = (t >= off) ? part[t - off] : 0;
    __syncthreads();
    part[t] += v;
    __syncthreads();
  }
  int run = part[t] - s;   // exclusive prefix of this thread's chunk
  for (int i = 0; i < 64; i++) {
    int id = i * 256 + t;
    int c = cnt[id];
    beg[id] = run; cur[id] = run;                       // coalesced
    run += c;
  }
}

__global__ __launch_bounds__(256) void scatter_kernel(
    const int* __restrict__ sid_pos, const int* __restrict__ qid_pos,
    int* __restrict__ cur_pos, int* __restrict__ csr_pos,
    const int* __restrict__ sid_neg, const int* __restrict__ qid_neg,
    int* __restrict__ cur_neg, int* __restrict__ csr_neg, int n) {
  const int* sid = blockIdx.y ? sid_neg : sid_pos;
  const int* qid = blockIdx.y ? qid_neg : qid_pos;
  int* cursor = blockIdx.y ? cur_neg : cur_pos;
  int* csr_qid = blockIdx.y ? csr_neg : csr_pos;
  int i = blockIdx.x * 256 + threadIdx.x;
  if (i < n) {
    int p = atomicAdd(&cursor[sid[i]], 1);
    csr_qid[p] = qid[i];
  }
}

// ---------------- main per-student kernel (both channels) ----------------
// Block = (student, channel). K/Vf history staged once in LDS. Then 8
// independent 32-lane groups each stream their own edges with ZERO barriers:
// stage own Q row (wave-local), score (v2f pk-fma), in-wave softmax,
// agg in fused space, sc2 dot, exp, atomics. Lane owns features {2c, 2c+1}.
__global__ __launch_bounds__(256) void main_kernel(
    const float* __restrict__ xKpos, const float* __restrict__ xKneg,
    const float* __restrict__ xVf, const float* __restrict__ xQ1,
    const float* __restrict__ xq2tab,
    const float* __restrict__ c2pos, const float* __restrict__ c2neg,
    const float* __restrict__ sQ, const float* __restrict__ sf,
    const int* __restrict__ hq_pos, const int* __restrict__ hc_pos,
    const int* __restrict__ hq_neg, const int* __restrict__ hc_neg,
    const int* __restrict__ beg_pos, const int* __restrict__ cntS_pos,
    const int* __restrict__ csr_pos,
    const int* __restrict__ beg_neg, const int* __restrict__ cntS_neg,
    const int* __restrict__ csr_neg,
    float* __restrict__ num_pos, float* __restrict__ den_pos,
    float* __restrict__ num_neg, float* __restrict__ den_neg)
{
  const int s = blockIdx.x;
  const int ch = blockIdx.y;
  const float* __restrict__ xK = ch ? xKneg : xKpos;
  const float* __restrict__ c2 = ch ? c2neg : c2pos;
  const int* __restrict__ hq = ch ? hq_neg : hq_pos;
  const int* __restrict__ hc = ch ? hc_neg : hc_pos;
  const int* __restrict__ beg = ch ? beg_neg : beg_pos;
  const int* __restrict__ cntS = ch ? cntS_neg : cntS_pos;
  const int* __restrict__ csr = ch ? csr_neg : csr_pos;
  float* __restrict__ num = ch ? num_neg : num_pos;
  float* __restrict__ den = ch ? den_neg : den_pos;

  const int t = threadIdx.x;
  __shared__ float Kl[HN * KPAD];   // 8704 B
  __shared__ float Vl[HN * 64];     // 8192 B
  __shared__ float Qg[8 * 64];      // 2048 B, per-group Q scratch
  __shared__ float Al[8 * 33];      // 1056 B
  __shared__ float sQl[64], sfl[64];
  __shared__ int hql[HN];

  const int hcnt = hc[s];
  if (t < HN) hql[t] = hq[s * HN + t];
  if (t >= 128 && t < 192) sQl[t - 128] = sQ[s * 64 + (t - 128)];
  if (t >= 192) sfl[t - 192] = sf[s * 64 + (t - 192)];
  __syncthreads();   // hql ready for gather
  for (int i = 0; i < 2; i++) {
    int idx = i * 256 + t;
    int h = idx >> 4, jj = idx & 15;
    int row = hql[h];
    *(v4f*)&Kl[h * KPAD + jj * 4] = *(const v4f*)&xK[row * 64 + jj * 4];
    *(v4f*)&Vl[h * 64 + jj * 4] = *(const v4f*)&xVf[row * 64 + jj * 4];
  }
  const int ebeg = beg[s];
  const int ne = cntS[s];
  __syncthreads();   // Kl/Vl ready — the ONLY barrier before the loop

  const float scale = 0.125f;
  const int e = t >> 5;       // group 0..7
  const int c = t & 31;       // lane in group: h for score, f-pair {2c,2c+1}
  float* Qrow = &Qg[e * 64];
  const v2f sq = *(const v2f*)&sQl[2 * c];
  const v2f sfv = *(const v2f*)&sfl[2 * c];
  const v4f* kp = (const v4f*)&Kl[c * KPAD];

  for (int i = e; i < ne; i += 8) {
    const int qq = csr[ebeg + i];
    v2f qv = *(const v2f*)&xQ1[qq * 64 + 2 * c] + sq;
    *(v2f*)&Qrow[2 * c] = qv;          // wave-local; compiler orders via lgkmcnt

    // score: lane c = history slot
    v2f acc = {0.f, 0.f};
    const v4f* qp = (const v4f*)Qrow;
#pragma unroll
    for (int k = 0; k < 16; k++) {
      v4f q4 = qp[k], k4 = kp[k];
      acc += q4.lo * k4.lo;
      acc += q4.hi * k4.hi;
    }
    float sc = (acc.x + acc.y) * scale;
    float m = (c < hcnt) ? sc : -1e30f;
    for (int k = 16; k >= 1; k >>= 1) m = fmaxf(m, __shfl_xor(m, k, 32));
    float ew = (c < hcnt) ? __expf(sc - m) : 0.f;
    float d = ew;
    for (int k = 16; k >= 1; k >>= 1) d += __shfl_xor(d, k, 32);
    float a = (d > 0.f) ? ew / d : 0.f;
    Al[e * 33 + c] = a;

    // agg in fused space: r = sf + a @ Vf_rows; lane owns f = {2c, 2c+1}
    v2f r = sfv;
#pragma unroll
    for (int hh = 0; hh < HN; hh++)
      r += Al[e * 33 + hh] * *(const v2f*)&Vl[hh * 64 + 2 * c];

    v2f x2 = *(const v2f*)&xq2tab[qq * 64 + 2 * c];
    float p = r.x * x2.x + r.y * x2.y;
    for (int k = 16; k >= 1; k >>= 1) p += __shfl_xor(p, k, 32);
    float sc2 = p * scale + c2[qq];
    float ew2 = __expf(sc2);
    atomicAdd(&num[qq * 64 + 2 * c], ew2 * r.x);
    atomicAdd(&num[qq * 64 + 2 * c + 1], ew2 * r.y);
    if (c == 0) atomicAdd(&den[qq], ew2);
  }
}

// ---------------- final projection ----------------
__global__ __launch_bounds__(256) void final_kernel(
    const float* __restrict__ num_pos, const float* __restrict__ den_pos,
    const float* __restrict__ num_neg, const float* __restrict__ den_neg,
    const float* __restrict__ W_V2, const float* __restrict__ b_V2,
    const float* __restrict__ W_proj, const float* __restrict__ b_proj,
    float* __restrict__ out)
{
  __shared__ float np[8 * 64], nn[8 * 64], hp[8 * 64], hn[8 * 64];
  int t = threadIdx.x;
  int j = t & 31, r = t >> 5;
  int q = blockIdx.x * 8 + r;
  if (t < 128) {
    *(v4f*)&np[t * 4] = *(const v4f*)&num_pos[blockIdx.x * 512 + t * 4];
    *(v4f*)&nn[t * 4] = *(const v4f*)&num_neg[blockIdx.x * 512 + t * 4];
  }
  __syncthreads();
  float dp = den_pos[q], dn = den_neg[q];
  float ip = (dp > 0.f) ? 1.f / dp : 0.f;
  float in_ = (dn > 0.f) ? 1.f / dn : 0.f;
  v2f zero = {0.f, 0.f};
  v2f bv = *(const v2f*)&b_V2[2 * j];
  v2f hpv = (dp > 0.f) ? bv : zero;
  v2f hnv = (dn > 0.f) ? bv : zero;
  for (int f = 0; f < 64; f++) {
    v2f w = *(const v2f*)&W_V2[f * 64 + 2 * j];
    hpv += (np[r * 64 + f] * ip) * w;
    hnv += (nn[r * 64 + f] * in_) * w;
  }
  *(v2f*)&hp[r * 64 + 2 * j] = hpv;
  *(v2f*)&hn[r * 64 + 2 * j] = hnv;
  __syncthreads();
  v2f o = *(const v2f*)&b_proj[2 * j];
  for (int f = 0; f < 64; f++) {
    o += hp[r * 64 + f] * *(const v2f*)&W_proj[f * 64 + 2 * j];
    o += hn[r * 64 + f] * *(const v2f*)&W_proj[(64 + f) * 64 + 2 * j];
  }
  *(v2f*)&out[q * 64 + 2 * j] = o;
}

extern "C" void kernel_launch(void* const* d_in, const int* in_sizes, int n_in,
                              void* d_out, int out_size, void* d_ws, size_t ws_size,
                              hipStream_t stream) {
  const float* x      = (const float*)d_in[0];
  const float* s_emb  = (const float*)d_in[1];
  const float* W_Q    = (const float*)d_in[2];
  const float* b_Q    = (const float*)d_in[3];
  const float* W_K    = (const float*)d_in[4];
  const float* b_K    = (const float*)d_in[5];
  const float* W_V    = (const float*)d_in[6];
  const float* b_V    = (const float*)d_in[7];
  const float* W_fuse = (const float*)d_in[8];
  const float* b_fuse = (const float*)d_in[9];
  const float* W_K2   = (const float*)d_in[10];
  const float* b_K2   = (const float*)d_in[11];
  const float* W_V2   = (const float*)d_in[12];
  const float* b_V2   = (const float*)d_in[13];
  const float* W_proj = (const float*)d_in[14];
  const float* b_proj = (const float*)d_in[15];
  const float* h1b    = (const float*)d_in[16];
  const float* h2b    = (const float*)d_in[17];
  const int* hq_pos   = (const int*)d_in[18];
  const int* hc_pos   = (const int*)d_in[19];
  const int* hq_neg   = (const int*)d_in[20];
  const int* hc_neg   = (const int*)d_in[21];
  const int* es_pos   = (const int*)d_in[22];
  const int* eq_pos   = (const int*)d_in[23];
  const int* es_neg   = (const int*)d_in[24];
  const int* eq_neg   = (const int*)d_in[25];
  float* out = (float*)d_out;

  size_t off = 0;
  char* base = (char*)d_ws;
  auto carve = [&](size_t bytes) -> void* {
    void* p = base + off;
    off += (bytes + 255) & ~(size_t)255;
    return p;
  };
  // zero-init region
  float* num_pos = (float*)carve((size_t)QN * 64 * 4);
  float* num_neg = (float*)carve((size_t)QN * 64 * 4);
  float* den_pos = (float*)carve((size_t)QN * 4);
  float* den_neg = (float*)carve((size_t)QN * 4);
  int* cnt_pos   = (int*)carve((size_t)SN * 4);
  int* cnt_neg   = (int*)carve((size_t)SN * 4);
  size_t zero_bytes = off;
  // non-zeroed
  float* xKpos = (float*)carve((size_t)QN * 64 * 4);
  float* xKneg = (float*)carve((size_t)QN * 64 * 4);
  float* xVf   = (float*)carve((size_t)QN * 64 * 4);
  float* xQ1   = (float*)carve((size_t)QN * 64 * 4);
  float* xq2   = (float*)carve((size_t)QN * 64 * 4);
  float* sQ    = (float*)carve((size_t)SN * 64 * 4);
  float* sf    = (float*)carve((size_t)SN * 64 * 4);
  float* c2pos = (float*)carve((size_t)QN * 4);
  float* c2neg = (float*)carve((size_t)QN * 4);
  int* beg_pos = (int*)carve((size_t)SN * 4);
  int* beg_neg = (int*)carve((size_t)SN * 4);
  int* cur_pos = (int*)carve((size_t)SN * 4);
  int* cur_neg = (int*)carve((size_t)SN * 4);
  int* csr_pos = (int*)carve((size_t)EN * 4);
  int* csr_neg = (int*)carve((size_t)EN * 4);
  if (off > ws_size) return;

  hipMemsetAsync(d_ws, 0, zero_bytes, stream);

  p1_kernel<<<QN / 8, 256, 0, stream>>>(x, W_K, b_K, W_V, b_V, W_Q, W_K2, b_K2,
                                        W_fuse, h1b, h2b, xKpos, xKneg, xVf, xQ1,
                                        xq2, c2pos, c2neg);
  p2_kernel<<<SN / 8, 256, 0, stream>>>(s_emb, W_Q, b_Q, W_fuse, b_fuse, sQ, sf);

  hist_kernel<<<dim3(EN / 256, 2), 256, 0, stream>>>(es_pos, es_neg, cnt_pos, cnt_neg, EN);
  scan_kernel<<<dim3(1, 2), 256, 0, stream>>>(cnt_pos, beg_pos, cur_pos,
                                              cnt_neg, beg_neg, cur_neg);
  scatter_kernel<<<dim3(EN / 256, 2), 256, 0, stream>>>(es_pos, eq_pos, cur_pos, csr_pos,
                                                        es_neg, eq_neg, cur_neg, csr_neg, EN);

  main_kernel<<<dim3(SN, 2), 256, 0, stream>>>(
      xKpos, xKneg, xVf, xQ1, xq2, c2pos, c2neg, sQ, sf,
      hq_pos, hc_pos, hq_neg, hc_neg,
      beg_pos, cnt_pos, csr_pos, beg_neg, cnt_neg, csr_neg,
      num_pos, den_pos, num_neg, den_neg);

  final_kernel<<<QN / 8, 256, 0, stream>>>(num_pos, den_pos, num_neg, den_neg,
                                           W_V2, b_V2, W_proj, b_proj, out);
}

// Round 5
// 607.812 us; speedup vs baseline: 1.2357x; 1.2357x over previous
//
#include <hip/hip_runtime.h>

typedef float v2f __attribute__((ext_vector_type(2)));
typedef float v4f __attribute__((ext_vector_type(4)));

#define QN 16384
#define SN 16384
#define HN 32
#define EN 393216
#define KPAD 68   // 17*16B rows: float4-aligned, measured 0 bank conflicts

// ---------------- merged prep kernel: p1 | p2 | hist ----------------
// p1 (blocks 0..2047): per-question tables.
//   xKpos/xKneg = x@W_K + b_K + h1_bias[ch]         (natural col order)
//   xQ1  = x@W_Q[0:64]                              (natural)
//   xVfp = (x@W_V + b_V) @ W_fuse[64:128]           (PAIR-PERMUTED: [2c]=col c, [2c+1]=col c+32)
//   xq2p = x @ W_K2^T                               (PAIR-PERMUTED)
//   c2{pos,neg}[q] = scale * sum_f x[q][f]*(b_K2[f] + h2_bias[ch][f])
// p2 (blocks 2048..4095): sQ = s_emb@W_Q[64:128]+b_Q (natural);
//   sfp = s_emb@W_fuse[0:64]+b_fuse (PAIR-PERMUTED)
// hist (blocks 4096..7167): per-student edge counts, both channels.
__global__ __launch_bounds__(256) void prep_kernel(
    const float* __restrict__ x, const float* __restrict__ s_emb,
    const float* __restrict__ W_Q, const float* __restrict__ b_Q,
    const float* __restrict__ W_K, const float* __restrict__ b_K,
    const float* __restrict__ W_V, const float* __restrict__ b_V,
    const float* __restrict__ W_fuse, const float* __restrict__ b_fuse,
    const float* __restrict__ W_K2, const float* __restrict__ b_K2,
    const float* __restrict__ h1b, const float* __restrict__ h2b,
    const int* __restrict__ es_pos, const int* __restrict__ es_neg,
    float* __restrict__ xKpos, float* __restrict__ xKneg,
    float* __restrict__ xVfp, float* __restrict__ xQ1, float* __restrict__ xq2p,
    float* __restrict__ c2pos, float* __restrict__ c2neg,
    float* __restrict__ sQ, float* __restrict__ sfp,
    int* __restrict__ cnt_pos, int* __restrict__ cnt_neg)
{
  __shared__ float xs[512];
  __shared__ float vs[512];
  __shared__ float wk2t[64 * 66];   // transposed W_K2, padded
  const int bid = blockIdx.x;
  const int t = threadIdx.x;
  const int j = t & 31, r = t >> 5;

  if (bid < 2048) {
    const int q = bid * 8 + r;
    if (t < 128) *(v4f*)&xs[t * 4] = *(const v4f*)&x[bid * 512 + t * 4];
    for (int i = 0; i < 16; i++) {
      int idx = i * 256 + t;
      wk2t[(idx & 63) * 66 + (idx >> 6)] = W_K2[idx];   // wk2t[b][a] = W_K2[a][b]
    }
    __syncthreads();

    v2f accK = *(const v2f*)&b_K[2 * j];
    v2f accV = *(const v2f*)&b_V[2 * j];
    v2f accQ = {0.f, 0.f};
    float a2x = 0.f, a2y = 0.f;
    for (int g = 0; g < 64; g++) {
      float xv = xs[r * 64 + g];
      accK += xv * *(const v2f*)&W_K[g * 64 + 2 * j];
      accV += xv * *(const v2f*)&W_V[g * 64 + 2 * j];
      accQ += xv * *(const v2f*)&W_Q[g * 64 + 2 * j];
      a2x += xv * wk2t[g * 66 + j];        // col j of x@W_K2^T
      a2y += xv * wk2t[g * 66 + j + 32];   // col j+32
    }
    *(v2f*)&xKpos[q * 64 + 2 * j] = accK + *(const v2f*)&h1b[2 * j];
    *(v2f*)&xKneg[q * 64 + 2 * j] = accK + *(const v2f*)&h1b[64 + 2 * j];
    *(v2f*)&xQ1[q * 64 + 2 * j] = accQ;
    v2f a2 = {a2x, a2y};
    *(v2f*)&xq2p[q * 64 + 2 * j] = a2;     // pair-permuted
    *(v2f*)&vs[r * 64 + 2 * j] = accV;

    v2f xv2 = *(const v2f*)&xs[r * 64 + 2 * j];
    v2f bb0 = *(const v2f*)&b_K2[2 * j] + *(const v2f*)&h2b[2 * j];
    v2f bb1 = *(const v2f*)&b_K2[2 * j] + *(const v2f*)&h2b[64 + 2 * j];
    v2f t0 = xv2 * bb0, t1 = xv2 * bb1;
    float p0 = t0.x + t0.y, p1v = t1.x + t1.y;
    for (int k = 16; k >= 1; k >>= 1) {
      p0 += __shfl_xor(p0, k, 32);
      p1v += __shfl_xor(p1v, k, 32);
    }
    if (j == 0) { c2pos[q] = p0 * 0.125f; c2neg[q] = p1v * 0.125f; }

    __syncthreads();
    float vfx = 0.f, vfy = 0.f;
    for (int g = 0; g < 64; g++) {
      float vv = vs[r * 64 + g];
      vfx += vv * W_fuse[(64 + g) * 64 + j];
      vfy += vv * W_fuse[(64 + g) * 64 + j + 32];
    }
    v2f vf = {vfx, vfy};
    *(v2f*)&xVfp[q * 64 + 2 * j] = vf;     // pair-permuted
  } else if (bid < 4096) {
    const int b2 = bid - 2048;
    const int s = b2 * 8 + r;
    if (t < 128) *(v4f*)&xs[t * 4] = *(const v4f*)&s_emb[b2 * 512 + t * 4];
    __syncthreads();
    v2f aq = *(const v2f*)&b_Q[2 * j];
    float afx = b_fuse[j], afy = b_fuse[j + 32];
    for (int g = 0; g < 64; g++) {
      float v = xs[r * 64 + g];
      aq += v * *(const v2f*)&W_Q[(64 + g) * 64 + 2 * j];
      afx += v * W_fuse[g * 64 + j];
      afy += v * W_fuse[g * 64 + j + 32];
    }
    *(v2f*)&sQ[s * 64 + 2 * j] = aq;
    v2f af = {afx, afy};
    *(v2f*)&sfp[s * 64 + 2 * j] = af;      // pair-permuted
  } else {
    const int hb = bid - 4096;
    const bool neg = hb >= 1536;
    const int* __restrict__ sid = neg ? es_neg : es_pos;
    int* __restrict__ cnt = neg ? cnt_neg : cnt_pos;
    const int i = (neg ? hb - 1536 : hb) * 256 + t;
    atomicAdd(&cnt[sid[i]], 1);
  }
}

// ---------------- CSR scan / scatter ----------------
// Coalesced permuted scan: ranges need only be disjoint, not ordered by s.
__global__ __launch_bounds__(256) void scan_kernel(
    const int* __restrict__ cnt_pos, int* __restrict__ beg_pos, int* __restrict__ cur_pos,
    const int* __restrict__ cnt_neg, int* __restrict__ beg_neg, int* __restrict__ cur_neg) {
  const int* cnt = blockIdx.y ? cnt_neg : cnt_pos;
  int* beg = blockIdx.y ? beg_neg : beg_pos;
  int* cur = blockIdx.y ? cur_neg : cur_pos;
  __shared__ int part[256];
  int t = threadIdx.x;
  int s = 0;
  for (int i = 0; i < 64; i++) s += cnt[i * 256 + t];   // coalesced
  part[t] = s;
  __syncthreads();
  for (int off = 1; off < 256; off <<= 1) {
    int v = (t >= off) ? part[t - off] : 0;
    __syncthreads();
    part[t] += v;
    __syncthreads();
  }
  int run = part[t] - s;
  for (int i = 0; i < 64; i++) {
    int id = i * 256 + t;
    int c = cnt[id];
    beg[id] = run; cur[id] = run;
    run += c;
  }
}

__global__ __launch_bounds__(256) void scatter_kernel(
    const int* __restrict__ sid_pos, const int* __restrict__ qid_pos,
    int* __restrict__ cur_pos, int* __restrict__ csr_pos,
    const int* __restrict__ sid_neg, const int* __restrict__ qid_neg,
    int* __restrict__ cur_neg, int* __restrict__ csr_neg, int n) {
  const int* sid = blockIdx.y ? sid_neg : sid_pos;
  const int* qid = blockIdx.y ? qid_neg : qid_pos;
  int* cursor = blockIdx.y ? cur_neg : cur_pos;
  int* csr_qid = blockIdx.y ? csr_neg : csr_pos;
  int i = blockIdx.x * 256 + threadIdx.x;
  if (i < n) {
    int p = atomicAdd(&cursor[sid[i]], 1);
    csr_qid[p] = qid[i];
  }
}

// ---------------- main per-student kernel (both channels) ----------------
// Block = (student, channel); 8 independent 32-lane groups; each group
// processes 4 EDGES AT ONCE so the K-row and V-row LDS reads are amortized
// 4x. Lane c owns history slot c (score) and feature pair {c, c+32} (agg,
// via pair-permuted V-side tables) -> ds_read_b64 AND contiguous atomics.
// Zero barriers in the main loop (all LDS scratch is group/wave-local).
__global__ __launch_bounds__(256, 4) void main_kernel(
    const float* __restrict__ xKpos, const float* __restrict__ xKneg,
    const float* __restrict__ xVfp, const float* __restrict__ xQ1,
    const float* __restrict__ xq2p,
    const float* __restrict__ c2pos, const float* __restrict__ c2neg,
    const float* __restrict__ sQ, const float* __restrict__ sfp,
    const int* __restrict__ hq_pos, const int* __restrict__ hc_pos,
    const int* __restrict__ hq_neg, const int* __restrict__ hc_neg,
    const int* __restrict__ beg_pos, const int* __restrict__ cntS_pos,
    const int* __restrict__ csr_pos,
    const int* __restrict__ beg_neg, const int* __restrict__ cntS_neg,
    const int* __restrict__ csr_neg,
    float* __restrict__ num_pos, float* __restrict__ den_pos,
    float* __restrict__ num_neg, float* __restrict__ den_neg)
{
  const int s = blockIdx.x;
  const int ch = blockIdx.y;
  const float* __restrict__ xK = ch ? xKneg : xKpos;
  const float* __restrict__ c2 = ch ? c2neg : c2pos;
  const int* __restrict__ hq = ch ? hq_neg : hq_pos;
  const int* __restrict__ hc = ch ? hc_neg : hc_pos;
  const int* __restrict__ beg = ch ? beg_neg : beg_pos;
  const int* __restrict__ cntS = ch ? cntS_neg : cntS_pos;
  const int* __restrict__ csr = ch ? csr_neg : csr_pos;
  float* __restrict__ num = ch ? num_neg : num_pos;
  float* __restrict__ den = ch ? den_neg : den_pos;

  const int t = threadIdx.x;
  __shared__ float Kl[HN * KPAD];   // 8704 B, natural order
  __shared__ float Vl[HN * 64];     // 8192 B, pair-permuted cols
  __shared__ float Qg[8 * 4 * 64];  // 8192 B, 4 staged Q rows per group
  __shared__ float Al[8 * 32 * 4];  // 4096 B, [group][slot][edge]
  __shared__ float sQl[64], sflp[64];
  __shared__ int hql[HN];

  const int hcnt = hc[s];
  if (t < HN) hql[t] = hq[s * HN + t];
  if (t >= 128 && t < 192) sQl[t - 128] = sQ[s * 64 + (t - 128)];
  if (t >= 192) sflp[t - 192] = sfp[s * 64 + (t - 192)];
  __syncthreads();
  for (int i = 0; i < 2; i++) {
    int idx = i * 256 + t;
    int h = idx >> 4, jj = idx & 15;
    int row = hql[h];
    *(v4f*)&Kl[h * KPAD + jj * 4] = *(const v4f*)&xK[row * 64 + jj * 4];
    *(v4f*)&Vl[h * 64 + jj * 4] = *(const v4f*)&xVfp[row * 64 + jj * 4];
  }
  const int ebeg = beg[s];
  const int ne = cntS[s];
  __syncthreads();

  const float scale = 0.125f;
  const int g = t >> 5;
  const int c = t & 31;
  float* __restrict__ Qb = &Qg[g * 256];
  float* __restrict__ Ab = &Al[g * 128];
  const v4f* kp = (const v4f*)&Kl[c * KPAD];
  const v2f sqv = *(const v2f*)&sQl[2 * c];    // natural pair (Q staging)
  const v2f sfv = *(const v2f*)&sflp[2 * c];   // permuted pair {c, c+32}

  for (int i0 = g * 4; i0 < ne; i0 += 32) {
    const int nb = ne - i0;   // >=1; guards clamp at 4
    int q0 = 0, q1 = 0, q2 = 0, q3 = 0;
    q0 = csr[ebeg + i0];
    { v2f qv = *(const v2f*)&xQ1[q0 * 64 + 2 * c] + sqv; *(v2f*)&Qb[2 * c] = qv; }
    if (nb > 1) { q1 = csr[ebeg + i0 + 1]; v2f qv = *(const v2f*)&xQ1[q1 * 64 + 2 * c] + sqv; *(v2f*)&Qb[64 + 2 * c] = qv; }
    if (nb > 2) { q2 = csr[ebeg + i0 + 2]; v2f qv = *(const v2f*)&xQ1[q2 * 64 + 2 * c] + sqv; *(v2f*)&Qb[128 + 2 * c] = qv; }
    if (nb > 3) { q3 = csr[ebeg + i0 + 3]; v2f qv = *(const v2f*)&xQ1[q3 * 64 + 2 * c] + sqv; *(v2f*)&Qb[192 + 2 * c] = qv; }

    // scores: lane c = history slot c; 4 edges share each K read
    float s0 = 0.f, s1 = 0.f, s2 = 0.f, s3 = 0.f;
#pragma unroll 4
    for (int k = 0; k < 16; k++) {
      v4f k4 = kp[k];
      v4f qa = ((const v4f*)&Qb[0])[k];
      s0 += qa.x * k4.x + qa.y * k4.y + qa.z * k4.z + qa.w * k4.w;
      v4f qb = ((const v4f*)&Qb[64])[k];
      s1 += qb.x * k4.x + qb.y * k4.y + qb.z * k4.z + qb.w * k4.w;
      v4f qc = ((const v4f*)&Qb[128])[k];
      s2 += qc.x * k4.x + qc.y * k4.y + qc.z * k4.z + qc.w * k4.w;
      v4f qd = ((const v4f*)&Qb[192])[k];
      s3 += qd.x * k4.x + qd.y * k4.y + qd.z * k4.z + qd.w * k4.w;
    }
    // softmax without max-pass (|sc*scale| <~ 3, exp-safe; math identical)
    const bool valid = (c < hcnt);
    float e0 = valid ? __expf(s0 * scale) : 0.f;
    float e1 = valid ? __expf(s1 * scale) : 0.f;
    float e2 = valid ? __expf(s2 * scale) : 0.f;
    float e3 = valid ? __expf(s3 * scale) : 0.f;
    float d0 = e0, d1 = e1, d2 = e2, d3 = e3;
    for (int k = 16; k >= 1; k >>= 1) {
      d0 += __shfl_xor(d0, k, 32);
      d1 += __shfl_xor(d1, k, 32);
      d2 += __shfl_xor(d2, k, 32);
      d3 += __shfl_xor(d3, k, 32);
    }
    v4f av;
    av.x = (d0 > 0.f) ? e0 / d0 : 0.f;
    av.y = (d1 > 0.f) ? e1 / d1 : 0.f;
    av.z = (d2 > 0.f) ? e2 / d2 : 0.f;
    av.w = (d3 > 0.f) ? e3 / d3 : 0.f;
    *(v4f*)&Ab[c * 4] = av;   // same-wave write/read (group-local region)

    // agg in fused pair space: r_e = sf + sum_h a[e][h] * Vf[h][{c,c+32}]
    v2f r0 = sfv, r1 = sfv, r2 = sfv, r3 = sfv;
#pragma unroll 8
    for (int h = 0; h < HN; h++) {
      v2f vv = *(const v2f*)&Vl[h * 64 + 2 * c];
      v4f a4 = *(const v4f*)&Ab[h * 4];   // broadcast: all 4 edges' a for slot h
      r0 += a4.x * vv;
      r1 += a4.y * vv;
      r2 += a4.z * vv;
      r3 += a4.w * vv;
    }

    // per-edge epilogue: sc2 dot, exp, coalesced atomics
    {
      v2f x2 = *(const v2f*)&xq2p[q0 * 64 + 2 * c];
      float p = r0.x * x2.x + r0.y * x2.y;
      for (int k = 16; k >= 1; k >>= 1) p += __shfl_xor(p, k, 32);
      float ew = __expf(p * scale + c2[q0]);
      atomicAdd(&num[q0 * 64 + c], ew * r0.x);
      atomicAdd(&num[q0 * 64 + 32 + c], ew * r0.y);
      if (c == 0) atomicAdd(&den[q0], ew);
    }
    if (nb > 1) {
      v2f x2 = *(const v2f*)&xq2p[q1 * 64 + 2 * c];
      float p = r1.x * x2.x + r1.y * x2.y;
      for (int k = 16; k >= 1; k >>= 1) p += __shfl_xor(p, k, 32);
      float ew = __expf(p * scale + c2[q1]);
      atomicAdd(&num[q1 * 64 + c], ew * r1.x);
      atomicAdd(&num[q1 * 64 + 32 + c], ew * r1.y);
      if (c == 0) atomicAdd(&den[q1], ew);
    }
    if (nb > 2) {
      v2f x2 = *(const v2f*)&xq2p[q2 * 64 + 2 * c];
      float p = r2.x * x2.x + r2.y * x2.y;
      for (int k = 16; k >= 1; k >>= 1) p += __shfl_xor(p, k, 32);
      float ew = __expf(p * scale + c2[q2]);
      atomicAdd(&num[q2 * 64 + c], ew * r2.x);
      atomicAdd(&num[q2 * 64 + 32 + c], ew * r2.y);
      if (c == 0) atomicAdd(&den[q2], ew);
    }
    if (nb > 3) {
      v2f x2 = *(const v2f*)&xq2p[q3 * 64 + 2 * c];
      float p = r3.x * x2.x + r3.y * x2.y;
      for (int k = 16; k >= 1; k >>= 1) p += __shfl_xor(p, k, 32);
      float ew = __expf(p * scale + c2[q3]);
      atomicAdd(&num[q3 * 64 + c], ew * r3.x);
      atomicAdd(&num[q3 * 64 + 32 + c], ew * r3.y);
      if (c == 0) atomicAdd(&den[q3], ew);
    }
  }
}

// ---------------- final projection ----------------
__global__ __launch_bounds__(256) void final_kernel(
    const float* __restrict__ num_pos, const float* __restrict__ den_pos,
    const float* __restrict__ num_neg, const float* __restrict__ den_neg,
    const float* __restrict__ W_V2, const float* __restrict__ b_V2,
    const float* __restrict__ W_proj, const float* __restrict__ b_proj,
    float* __restrict__ out)
{
  __shared__ float np[8 * 64], nn[8 * 64], hp[8 * 64], hn[8 * 64];
  int t = threadIdx.x;
  int j = t & 31, r = t >> 5;
  int q = blockIdx.x * 8 + r;
  if (t < 128) {
    *(v4f*)&np[t * 4] = *(const v4f*)&num_pos[blockIdx.x * 512 + t * 4];
    *(v4f*)&nn[t * 4] = *(const v4f*)&num_neg[blockIdx.x * 512 + t * 4];
  }
  __syncthreads();
  float dp = den_pos[q], dn = den_neg[q];
  float ip = (dp > 0.f) ? 1.f / dp : 0.f;
  float in_ = (dn > 0.f) ? 1.f / dn : 0.f;
  v2f zero = {0.f, 0.f};
  v2f bv = *(const v2f*)&b_V2[2 * j];
  v2f hpv = (dp > 0.f) ? bv : zero;
  v2f hnv = (dn > 0.f) ? bv : zero;
  for (int f = 0; f < 64; f++) {
    v2f w = *(const v2f*)&W_V2[f * 64 + 2 * j];
    hpv += (np[r * 64 + f] * ip) * w;
    hnv += (nn[r * 64 + f] * in_) * w;
  }
  *(v2f*)&hp[r * 64 + 2 * j] = hpv;
  *(v2f*)&hn[r * 64 + 2 * j] = hnv;
  __syncthreads();
  v2f o = *(const v2f*)&b_proj[2 * j];
  for (int f = 0; f < 64; f++) {
    o += hp[r * 64 + f] * *(const v2f*)&W_proj[f * 64 + 2 * j];
    o += hn[r * 64 + f] * *(const v2f*)&W_proj[(64 + f) * 64 + 2 * j];
  }
  *(v2f*)&out[q * 64 + 2 * j] = o;
}

extern "C" void kernel_launch(void* const* d_in, const int* in_sizes, int n_in,
                              void* d_out, int out_size, void* d_ws, size_t ws_size,
                              hipStream_t stream) {
  const float* x      = (const float*)d_in[0];
  const float* s_emb  = (const float*)d_in[1];
  const float* W_Q    = (const float*)d_in[2];
  const float* b_Q    = (const float*)d_in[3];
  const float* W_K    = (const float*)d_in[4];
  const float* b_K    = (const float*)d_in[5];
  const float* W_V    = (const float*)d_in[6];
  const float* b_V    = (const float*)d_in[7];
  const float* W_fuse = (const float*)d_in[8];
  const float* b_fuse = (const float*)d_in[9];
  const float* W_K2   = (const float*)d_in[10];
  const float* b_K2   = (const float*)d_in[11];
  const float* W_V2   = (const float*)d_in[12];
  const float* b_V2   = (const float*)d_in[13];
  const float* W_proj = (const float*)d_in[14];
  const float* b_proj = (const float*)d_in[15];
  const float* h1b    = (const float*)d_in[16];
  const float* h2b    = (const float*)d_in[17];
  const int* hq_pos   = (const int*)d_in[18];
  const int* hc_pos   = (const int*)d_in[19];
  const int* hq_neg   = (const int*)d_in[20];
  const int* hc_neg   = (const int*)d_in[21];
  const int* es_pos   = (const int*)d_in[22];
  const int* eq_pos   = (const int*)d_in[23];
  const int* es_neg   = (const int*)d_in[24];
  const int* eq_neg   = (const int*)d_in[25];
  float* out = (float*)d_out;

  size_t off = 0;
  char* base = (char*)d_ws;
  auto carve = [&](size_t bytes) -> void* {
    void* p = base + off;
    off += (bytes + 255) & ~(size_t)255;
    return p;
  };
  // zero-init region
  float* num_pos = (float*)carve((size_t)QN * 64 * 4);
  float* num_neg = (float*)carve((size_t)QN * 64 * 4);
  float* den_pos = (float*)carve((size_t)QN * 4);
  float* den_neg = (float*)carve((size_t)QN * 4);
  int* cnt_pos   = (int*)carve((size_t)SN * 4);
  int* cnt_neg   = (int*)carve((size_t)SN * 4);
  size_t zero_bytes = off;
  // non-zeroed
  float* xKpos = (float*)carve((size_t)QN * 64 * 4);
  float* xKneg = (float*)carve((size_t)QN * 64 * 4);
  float* xVfp  = (float*)carve((size_t)QN * 64 * 4);
  float* xQ1   = (float*)carve((size_t)QN * 64 * 4);
  float* xq2p  = (float*)carve((size_t)QN * 64 * 4);
  float* sQ    = (float*)carve((size_t)SN * 64 * 4);
  float* sfp   = (float*)carve((size_t)SN * 64 * 4);
  float* c2pos = (float*)carve((size_t)QN * 4);
  float* c2neg = (float*)carve((size_t)QN * 4);
  int* beg_pos = (int*)carve((size_t)SN * 4);
  int* beg_neg = (int*)carve((size_t)SN * 4);
  int* cur_pos = (int*)carve((size_t)SN * 4);
  int* cur_neg = (int*)carve((size_t)SN * 4);
  int* csr_pos = (int*)carve((size_t)EN * 4);
  int* csr_neg = (int*)carve((size_t)EN * 4);
  if (off > ws_size) return;

  hipMemsetAsync(d_ws, 0, zero_bytes, stream);

  prep_kernel<<<4096 + 2 * (EN / 256), 256, 0, stream>>>(
      x, s_emb, W_Q, b_Q, W_K, b_K, W_V, b_V, W_fuse, b_fuse, W_K2, b_K2,
      h1b, h2b, es_pos, es_neg,
      xKpos, xKneg, xVfp, xQ1, xq2p, c2pos, c2neg, sQ, sfp,
      cnt_pos, cnt_neg);

  scan_kernel<<<dim3(1, 2), 256, 0, stream>>>(cnt_pos, beg_pos, cur_pos,
                                              cnt_neg, beg_neg, cur_neg);
  scatter_kernel<<<dim3(EN / 256, 2), 256, 0, stream>>>(es_pos, eq_pos, cur_pos, csr_pos,
                                                        es_neg, eq_neg, cur_neg, csr_neg, EN);

  main_kernel<<<dim3(SN, 2), 256, 0, stream>>>(
      xKpos, xKneg, xVfp, xQ1, xq2p, c2pos, c2neg, sQ, sfp,
      hq_pos, hc_pos, hq_neg, hc_neg,
      beg_pos, cnt_pos, csr_pos, beg_neg, cnt_neg, csr_neg,
      num_pos, den_pos, num_neg, den_neg);

  final_kernel<<<QN / 8, 256, 0, stream>>>(num_pos, den_pos, num_neg, den_neg,
                                           W_V2, b_V2, W_proj, b_proj, out);
}

// Round 6
// 602.375 us; speedup vs baseline: 1.2468x; 1.0090x over previous
//
#include <hip/hip_runtime.h>

typedef float v2f __attribute__((ext_vector_type(2)));
typedef float v4f __attribute__((ext_vector_type(4)));

#define QN 16384
#define SN 16384
#define HN 32
#define EN 393216
#define KPAD 68   // 17*16B rows: float4-aligned, measured 0 bank conflicts

// ---------------- merged prep kernel: p1 | p2 | hist ----------------
// p1 (blocks 0..2047): per-question tables.
//   xKpos/xKneg = x@W_K + b_K + h1_bias[ch]         (natural col order)
//   xQ1  = x@W_Q[0:64]                              (natural)
//   xVfp = (x@W_V + b_V) @ W_fuse[64:128]           (PAIR-PERMUTED: [2c]=col c, [2c+1]=col c+32)
//   xq2p = x @ W_K2^T                               (PAIR-PERMUTED)
//   c2{pos,neg}[q] = scale * sum_f x[q][f]*(b_K2[f] + h2_bias[ch][f])
// p2 (blocks 2048..4095): sQ = s_emb@W_Q[64:128]+b_Q (natural);
//   sfp = s_emb@W_fuse[0:64]+b_fuse (PAIR-PERMUTED)
// hist (blocks 4096..7167): per-student edge counts, both channels.
__global__ __launch_bounds__(256) void prep_kernel(
    const float* __restrict__ x, const float* __restrict__ s_emb,
    const float* __restrict__ W_Q, const float* __restrict__ b_Q,
    const float* __restrict__ W_K, const float* __restrict__ b_K,
    const float* __restrict__ W_V, const float* __restrict__ b_V,
    const float* __restrict__ W_fuse, const float* __restrict__ b_fuse,
    const float* __restrict__ W_K2, const float* __restrict__ b_K2,
    const float* __restrict__ h1b, const float* __restrict__ h2b,
    const int* __restrict__ es_pos, const int* __restrict__ es_neg,
    float* __restrict__ xKpos, float* __restrict__ xKneg,
    float* __restrict__ xVfp, float* __restrict__ xQ1, float* __restrict__ xq2p,
    float* __restrict__ c2pos, float* __restrict__ c2neg,
    float* __restrict__ sQ, float* __restrict__ sfp,
    int* __restrict__ cnt_pos, int* __restrict__ cnt_neg)
{
  __shared__ float xs[512];
  __shared__ float vs[512];
  __shared__ float wk2t[64 * 66];   // transposed W_K2, padded
  const int bid = blockIdx.x;
  const int t = threadIdx.x;
  const int j = t & 31, r = t >> 5;

  if (bid < 2048) {
    const int q = bid * 8 + r;
    if (t < 128) *(v4f*)&xs[t * 4] = *(const v4f*)&x[bid * 512 + t * 4];
    for (int i = 0; i < 16; i++) {
      int idx = i * 256 + t;
      wk2t[(idx & 63) * 66 + (idx >> 6)] = W_K2[idx];   // wk2t[b][a] = W_K2[a][b]
    }
    __syncthreads();

    v2f accK = *(const v2f*)&b_K[2 * j];
    v2f accV = *(const v2f*)&b_V[2 * j];
    v2f accQ = {0.f, 0.f};
    float a2x = 0.f, a2y = 0.f;
    for (int g = 0; g < 64; g++) {
      float xv = xs[r * 64 + g];
      accK += xv * *(const v2f*)&W_K[g * 64 + 2 * j];
      accV += xv * *(const v2f*)&W_V[g * 64 + 2 * j];
      accQ += xv * *(const v2f*)&W_Q[g * 64 + 2 * j];
      a2x += xv * wk2t[g * 66 + j];        // col j of x@W_K2^T
      a2y += xv * wk2t[g * 66 + j + 32];   // col j+32
    }
    *(v2f*)&xKpos[q * 64 + 2 * j] = accK + *(const v2f*)&h1b[2 * j];
    *(v2f*)&xKneg[q * 64 + 2 * j] = accK + *(const v2f*)&h1b[64 + 2 * j];
    *(v2f*)&xQ1[q * 64 + 2 * j] = accQ;
    v2f a2 = {a2x, a2y};
    *(v2f*)&xq2p[q * 64 + 2 * j] = a2;     // pair-permuted
    *(v2f*)&vs[r * 64 + 2 * j] = accV;

    v2f xv2 = *(const v2f*)&xs[r * 64 + 2 * j];
    v2f bb0 = *(const v2f*)&b_K2[2 * j] + *(const v2f*)&h2b[2 * j];
    v2f bb1 = *(const v2f*)&b_K2[2 * j] + *(const v2f*)&h2b[64 + 2 * j];
    v2f t0 = xv2 * bb0, t1 = xv2 * bb1;
    float p0 = t0.x + t0.y, p1v = t1.x + t1.y;
    for (int k = 16; k >= 1; k >>= 1) {
      p0 += __shfl_xor(p0, k, 32);
      p1v += __shfl_xor(p1v, k, 32);
    }
    if (j == 0) { c2pos[q] = p0 * 0.125f; c2neg[q] = p1v * 0.125f; }

    __syncthreads();
    float vfx = 0.f, vfy = 0.f;
    for (int g = 0; g < 64; g++) {
      float vv = vs[r * 64 + g];
      vfx += vv * W_fuse[(64 + g) * 64 + j];
      vfy += vv * W_fuse[(64 + g) * 64 + j + 32];
    }
    v2f vf = {vfx, vfy};
    *(v2f*)&xVfp[q * 64 + 2 * j] = vf;     // pair-permuted
  } else if (bid < 4096) {
    const int b2 = bid - 2048;
    const int s = b2 * 8 + r;
    if (t < 128) *(v4f*)&xs[t * 4] = *(const v4f*)&s_emb[b2 * 512 + t * 4];
    __syncthreads();
    v2f aq = *(const v2f*)&b_Q[2 * j];
    float afx = b_fuse[j], afy = b_fuse[j + 32];
    for (int g = 0; g < 64; g++) {
      float v = xs[r * 64 + g];
      aq += v * *(const v2f*)&W_Q[(64 + g) * 64 + 2 * j];
      afx += v * W_fuse[g * 64 + j];
      afy += v * W_fuse[g * 64 + j + 32];
    }
    *(v2f*)&sQ[s * 64 + 2 * j] = aq;
    v2f af = {afx, afy};
    *(v2f*)&sfp[s * 64 + 2 * j] = af;      // pair-permuted
  } else {
    const int hb = bid - 4096;
    const bool neg = hb >= 1536;
    const int* __restrict__ sid = neg ? es_neg : es_pos;
    int* __restrict__ cnt = neg ? cnt_neg : cnt_pos;
    const int i = (neg ? hb - 1536 : hb) * 256 + t;
    atomicAdd(&cnt[sid[i]], 1);
  }
}

// ---------------- CSR scan / scatter ----------------
__global__ __launch_bounds__(256) void scan_kernel(
    const int* __restrict__ cnt_pos, int* __restrict__ beg_pos, int* __restrict__ cur_pos,
    const int* __restrict__ cnt_neg, int* __restrict__ beg_neg, int* __restrict__ cur_neg) {
  const int* cnt = blockIdx.y ? cnt_neg : cnt_pos;
  int* beg = blockIdx.y ? beg_neg : beg_pos;
  int* cur = blockIdx.y ? cur_neg : cur_pos;
  __shared__ int part[256];
  int t = threadIdx.x;
  int s = 0;
  for (int i = 0; i < 64; i++) s += cnt[i * 256 + t];   // coalesced
  part[t] = s;
  __syncthreads();
  for (int off = 1; off < 256; off <<= 1) {
    int v = (t >= off) ? part[t - off] : 0;
    __syncthreads();
    part[t] += v;
    __syncthreads();
  }
  int run = part[t] - s;
  for (int i = 0; i < 64; i++) {
    int id = i * 256 + t;
    int c = cnt[id];
    beg[id] = run; cur[id] = run;
    run += c;
  }
}

__global__ __launch_bounds__(256) void scatter_kernel(
    const int* __restrict__ sid_pos, const int* __restrict__ qid_pos,
    int* __restrict__ cur_pos, int* __restrict__ csr_pos,
    const int* __restrict__ sid_neg, const int* __restrict__ qid_neg,
    int* __restrict__ cur_neg, int* __restrict__ csr_neg, int n) {
  const int* sid = blockIdx.y ? sid_neg : sid_pos;
  const int* qid = blockIdx.y ? qid_neg : qid_pos;
  int* cursor = blockIdx.y ? cur_neg : cur_pos;
  int* csr_qid = blockIdx.y ? csr_neg : csr_pos;
  int i = blockIdx.x * 256 + threadIdx.x;
  if (i < n) {
    int p = atomicAdd(&cursor[sid[i]], 1);
    csr_qid[p] = qid[i];
  }
}

// ---------------- main per-student kernel (both channels) ----------------
// Block = (student, channel); 8 independent 32-lane groups; 4 edges per
// batch amortize K/V LDS reads; REGISTER PREFETCH of next batch's
// {csr, xQ1+sQ, xq2p, c2} bundle hides the 2-hop global latency chain
// under the current batch's compute. Zero barriers in the main loop.
#define LDBATCH(BASE, Q0,Q1,Q2,Q3, A0,A1,A2,A3, X0,X1,X2,X3, C0,C1,C2,C3) do { \
    int _m = ne - 1; \
    Q0 = csr[ebeg + (BASE)]; \
    Q1 = csr[ebeg + min((BASE) + 1, _m)]; \
    Q2 = csr[ebeg + min((BASE) + 2, _m)]; \
    Q3 = csr[ebeg + min((BASE) + 3, _m)]; \
    A0 = *(const v2f*)&xQ1[(size_t)Q0 * 64 + 2 * c] + sqv; \
    A1 = *(const v2f*)&xQ1[(size_t)Q1 * 64 + 2 * c] + sqv; \
    A2 = *(const v2f*)&xQ1[(size_t)Q2 * 64 + 2 * c] + sqv; \
    A3 = *(const v2f*)&xQ1[(size_t)Q3 * 64 + 2 * c] + sqv; \
    X0 = *(const v2f*)&xq2p[(size_t)Q0 * 64 + 2 * c]; \
    X1 = *(const v2f*)&xq2p[(size_t)Q1 * 64 + 2 * c]; \
    X2 = *(const v2f*)&xq2p[(size_t)Q2 * 64 + 2 * c]; \
    X3 = *(const v2f*)&xq2p[(size_t)Q3 * 64 + 2 * c]; \
    C0 = c2[Q0]; C1 = c2[Q1]; C2 = c2[Q2]; C3 = c2[Q3]; \
  } while (0)

__global__ __launch_bounds__(256, 5) void main_kernel(
    const float* __restrict__ xKpos, const float* __restrict__ xKneg,
    const float* __restrict__ xVfp, const float* __restrict__ xQ1,
    const float* __restrict__ xq2p,
    const float* __restrict__ c2pos, const float* __restrict__ c2neg,
    const float* __restrict__ sQ, const float* __restrict__ sfp,
    const int* __restrict__ hq_pos, const int* __restrict__ hc_pos,
    const int* __restrict__ hq_neg, const int* __restrict__ hc_neg,
    const int* __restrict__ beg_pos, const int* __restrict__ cntS_pos,
    const int* __restrict__ csr_pos,
    const int* __restrict__ beg_neg, const int* __restrict__ cntS_neg,
    const int* __restrict__ csr_neg,
    float* __restrict__ num_pos, float* __restrict__ den_pos,
    float* __restrict__ num_neg, float* __restrict__ den_neg)
{
  const int s = blockIdx.x;
  const int ch = blockIdx.y;
  const float* __restrict__ xK = ch ? xKneg : xKpos;
  const float* __restrict__ c2 = ch ? c2neg : c2pos;
  const int* __restrict__ hq = ch ? hq_neg : hq_pos;
  const int* __restrict__ hc = ch ? hc_neg : hc_pos;
  const int* __restrict__ beg = ch ? beg_neg : beg_pos;
  const int* __restrict__ cntS = ch ? cntS_neg : cntS_pos;
  const int* __restrict__ csr = ch ? csr_neg : csr_pos;
  float* __restrict__ num = ch ? num_neg : num_pos;
  float* __restrict__ den = ch ? den_neg : den_pos;

  const int t = threadIdx.x;
  __shared__ float Kl[HN * KPAD];   // 8704 B, natural order
  __shared__ float Vl[HN * 64];     // 8192 B, pair-permuted cols
  __shared__ float Qg[8 * 4 * 64];  // 8192 B, 4 staged Q rows per group
  __shared__ float Al[8 * 32 * 4];  // 4096 B, [group][slot][edge]
  __shared__ int hql[HN];

  const int hcnt = hc[s];
  if (t < HN) hql[t] = hq[s * HN + t];
  __syncthreads();
  for (int i = 0; i < 2; i++) {
    int idx = i * 256 + t;
    int h = idx >> 4, jj = idx & 15;
    int row = hql[h];
    *(v4f*)&Kl[h * KPAD + jj * 4] = *(const v4f*)&xK[(size_t)row * 64 + jj * 4];
    *(v4f*)&Vl[h * 64 + jj * 4] = *(const v4f*)&xVfp[(size_t)row * 64 + jj * 4];
  }
  const int ebeg = beg[s];
  const int ne = cntS[s];
  __syncthreads();

  const float scale = 0.125f;
  const int g = t >> 5;
  const int c = t & 31;
  float* __restrict__ Qb = &Qg[g * 256];
  float* __restrict__ Ab = &Al[g * 128];
  const v4f* kp = (const v4f*)&Kl[c * KPAD];
  const v2f sqv = *(const v2f*)&sQ[(size_t)s * 64 + 2 * c];    // natural pair
  const v2f sfv = *(const v2f*)&sfp[(size_t)s * 64 + 2 * c];   // permuted pair {c,c+32}

  int i0 = g * 4;
  if (i0 < ne) {
    int q0, q1, q2, q3;
    v2f a0, a1, a2, a3, x20, x21, x22, x23;
    float cc0, cc1, cc2, cc3;
    LDBATCH(i0, q0, q1, q2, q3, a0, a1, a2, a3, x20, x21, x22, x23, cc0, cc1, cc2, cc3);

    for (; i0 < ne; i0 += 32) {
      const int nb = ne - i0;
      // stage current Q rows (wave-local; compiler orders via lgkmcnt)
      *(v2f*)&Qb[2 * c] = a0;
      *(v2f*)&Qb[64 + 2 * c] = a1;
      *(v2f*)&Qb[128 + 2 * c] = a2;
      *(v2f*)&Qb[192 + 2 * c] = a3;

      // issue next-batch prefetch (overlaps all compute below)
      int n0, n1, n2, n3;
      v2f na0, na1, na2, na3, nx0, nx1, nx2, nx3;
      float nc0, nc1, nc2, nc3;
      const bool more = (i0 + 32) < ne;
      if (more) {
        LDBATCH(i0 + 32, n0, n1, n2, n3, na0, na1, na2, na3,
                nx0, nx1, nx2, nx3, nc0, nc1, nc2, nc3);
      }

      // scores: lane c = history slot c; 4 edges share each K read
      float s0 = 0.f, s1 = 0.f, s2 = 0.f, s3 = 0.f;
#pragma unroll 4
      for (int k = 0; k < 16; k++) {
        v4f k4 = kp[k];
        v4f qa = ((const v4f*)&Qb[0])[k];
        s0 += qa.x * k4.x + qa.y * k4.y + qa.z * k4.z + qa.w * k4.w;
        v4f qb = ((const v4f*)&Qb[64])[k];
        s1 += qb.x * k4.x + qb.y * k4.y + qb.z * k4.z + qb.w * k4.w;
        v4f qc = ((const v4f*)&Qb[128])[k];
        s2 += qc.x * k4.x + qc.y * k4.y + qc.z * k4.z + qc.w * k4.w;
        v4f qd = ((const v4f*)&Qb[192])[k];
        s3 += qd.x * k4.x + qd.y * k4.y + qd.z * k4.z + qd.w * k4.w;
      }
      // softmax without max-pass (|sc*scale| <~ 3, exp-safe; math identical)
      const bool valid = (c < hcnt);
      float e0 = valid ? __expf(s0 * scale) : 0.f;
      float e1 = valid ? __expf(s1 * scale) : 0.f;
      float e2 = valid ? __expf(s2 * scale) : 0.f;
      float e3 = valid ? __expf(s3 * scale) : 0.f;
      float d0 = e0, d1 = e1, d2 = e2, d3 = e3;
      for (int k = 16; k >= 1; k >>= 1) {
        d0 += __shfl_xor(d0, k, 32);
        d1 += __shfl_xor(d1, k, 32);
        d2 += __shfl_xor(d2, k, 32);
        d3 += __shfl_xor(d3, k, 32);
      }
      v4f av;
      av.x = (d0 > 0.f) ? e0 / d0 : 0.f;
      av.y = (d1 > 0.f) ? e1 / d1 : 0.f;
      av.z = (d2 > 0.f) ? e2 / d2 : 0.f;
      av.w = (d3 > 0.f) ? e3 / d3 : 0.f;
      *(v4f*)&Ab[c * 4] = av;   // same-wave write/read (group-local region)

      // agg in fused pair space: r_e = sf + sum_h a[e][h] * Vf[h][{c,c+32}]
      v2f r0 = sfv, r1 = sfv, r2 = sfv, r3 = sfv;
#pragma unroll 8
      for (int h = 0; h < HN; h++) {
        v2f vv = *(const v2f*)&Vl[h * 64 + 2 * c];
        v4f a4 = *(const v4f*)&Ab[h * 4];   // broadcast read
        r0 += a4.x * vv;
        r1 += a4.y * vv;
        r2 += a4.z * vv;
        r3 += a4.w * vv;
      }

      // per-edge epilogue: sc2 dot, exp, coalesced atomics
      {
        float p = r0.x * x20.x + r0.y * x20.y;
        for (int k = 16; k >= 1; k >>= 1) p += __shfl_xor(p, k, 32);
        float ew = __expf(p * scale + cc0);
        atomicAdd(&num[(size_t)q0 * 64 + c], ew * r0.x);
        atomicAdd(&num[(size_t)q0 * 64 + 32 + c], ew * r0.y);
        if (c == 0) atomicAdd(&den[q0], ew);
      }
      if (nb > 1) {
        float p = r1.x * x21.x + r1.y * x21.y;
        for (int k = 16; k >= 1; k >>= 1) p += __shfl_xor(p, k, 32);
        float ew = __expf(p * scale + cc1);
        atomicAdd(&num[(size_t)q1 * 64 + c], ew * r1.x);
        atomicAdd(&num[(size_t)q1 * 64 + 32 + c], ew * r1.y);
        if (c == 0) atomicAdd(&den[q1], ew);
      }
      if (nb > 2) {
        float p = r2.x * x22.x + r2.y * x22.y;
        for (int k = 16; k >= 1; k >>= 1) p += __shfl_xor(p, k, 32);
        float ew = __expf(p * scale + cc2);
        atomicAdd(&num[(size_t)q2 * 64 + c], ew * r2.x);
        atomicAdd(&num[(size_t)q2 * 64 + 32 + c], ew * r2.y);
        if (c == 0) atomicAdd(&den[q2], ew);
      }
      if (nb > 3) {
        float p = r3.x * x23.x + r3.y * x23.y;
        for (int k = 16; k >= 1; k >>= 1) p += __shfl_xor(p, k, 32);
        float ew = __expf(p * scale + cc3);
        atomicAdd(&num[(size_t)q3 * 64 + c], ew * r3.x);
        atomicAdd(&num[(size_t)q3 * 64 + 32 + c], ew * r3.y);
        if (c == 0) atomicAdd(&den[q3], ew);
      }

      // rotate prefetch -> current
      q0 = n0; q1 = n1; q2 = n2; q3 = n3;
      a0 = na0; a1 = na1; a2 = na2; a3 = na3;
      x20 = nx0; x21 = nx1; x22 = nx2; x23 = nx3;
      cc0 = nc0; cc1 = nc1; cc2 = nc2; cc3 = nc3;
    }
  }
}

// ---------------- final projection ----------------
__global__ __launch_bounds__(256) void final_kernel(
    const float* __restrict__ num_pos, const float* __restrict__ den_pos,
    const float* __restrict__ num_neg, const float* __restrict__ den_neg,
    const float* __restrict__ W_V2, const float* __restrict__ b_V2,
    const float* __restrict__ W_proj, const float* __restrict__ b_proj,
    float* __restrict__ out)
{
  __shared__ float np[8 * 64], nn[8 * 64], hp[8 * 64], hn[8 * 64];
  int t = threadIdx.x;
  int j = t & 31, r = t >> 5;
  int q = blockIdx.x * 8 + r;
  if (t < 128) {
    *(v4f*)&np[t * 4] = *(const v4f*)&num_pos[blockIdx.x * 512 + t * 4];
    *(v4f*)&nn[t * 4] = *(const v4f*)&num_neg[blockIdx.x * 512 + t * 4];
  }
  __syncthreads();
  float dp = den_pos[q], dn = den_neg[q];
  float ip = (dp > 0.f) ? 1.f / dp : 0.f;
  float in_ = (dn > 0.f) ? 1.f / dn : 0.f;
  v2f zero = {0.f, 0.f};
  v2f bv = *(const v2f*)&b_V2[2 * j];
  v2f hpv = (dp > 0.f) ? bv : zero;
  v2f hnv = (dn > 0.f) ? bv : zero;
  for (int f = 0; f < 64; f++) {
    v2f w = *(const v2f*)&W_V2[f * 64 + 2 * j];
    hpv += (np[r * 64 + f] * ip) * w;
    hnv += (nn[r * 64 + f] * in_) * w;
  }
  *(v2f*)&hp[r * 64 + 2 * j] = hpv;
  *(v2f*)&hn[r * 64 + 2 * j] = hnv;
  __syncthreads();
  v2f o = *(const v2f*)&b_proj[2 * j];
  for (int f = 0; f < 64; f++) {
    o += hp[r * 64 + f] * *(const v2f*)&W_proj[f * 64 + 2 * j];
    o += hn[r * 64 + f] * *(const v2f*)&W_proj[(64 + f) * 64 + 2 * j];
  }
  *(v2f*)&out[q * 64 + 2 * j] = o;
}

extern "C" void kernel_launch(void* const* d_in, const int* in_sizes, int n_in,
                              void* d_out, int out_size, void* d_ws, size_t ws_size,
                              hipStream_t stream) {
  const float* x      = (const float*)d_in[0];
  const float* s_emb  = (const float*)d_in[1];
  const float* W_Q    = (const float*)d_in[2];
  const float* b_Q    = (const float*)d_in[3];
  const float* W_K    = (const float*)d_in[4];
  const float* b_K    = (const float*)d_in[5];
  const float* W_V    = (const float*)d_in[6];
  const float* b_V    = (const float*)d_in[7];
  const float* W_fuse = (const float*)d_in[8];
  const float* b_fuse = (const float*)d_in[9];
  const float* W_K2   = (const float*)d_in[10];
  const float* b_K2   = (const float*)d_in[11];
  const float* W_V2   = (const float*)d_in[12];
  const float* b_V2   = (const float*)d_in[13];
  const float* W_proj = (const float*)d_in[14];
  const float* b_proj = (const float*)d_in[15];
  const float* h1b    = (const float*)d_in[16];
  const float* h2b    = (const float*)d_in[17];
  const int* hq_pos   = (const int*)d_in[18];
  const int* hc_pos   = (const int*)d_in[19];
  const int* hq_neg   = (const int*)d_in[20];
  const int* hc_neg   = (const int*)d_in[21];
  const int* es_pos   = (const int*)d_in[22];
  const int* eq_pos   = (const int*)d_in[23];
  const int* es_neg   = (const int*)d_in[24];
  const int* eq_neg   = (const int*)d_in[25];
  float* out = (float*)d_out;

  size_t off = 0;
  char* base = (char*)d_ws;
  auto carve = [&](size_t bytes) -> void* {
    void* p = base + off;
    off += (bytes + 255) & ~(size_t)255;
    return p;
  };
  // zero-init region
  float* num_pos = (float*)carve((size_t)QN * 64 * 4);
  float* num_neg = (float*)carve((size_t)QN * 64 * 4);
  float* den_pos = (float*)carve((size_t)QN * 4);
  float* den_neg = (float*)carve((size_t)QN * 4);
  int* cnt_pos   = (int*)carve((size_t)SN * 4);
  int* cnt_neg   = (int*)carve((size_t)SN * 4);
  size_t zero_bytes = off;
  // non-zeroed
  float* xKpos = (float*)carve((size_t)QN * 64 * 4);
  float* xKneg = (float*)carve((size_t)QN * 64 * 4);
  float* xVfp  = (float*)carve((size_t)QN * 64 * 4);
  float* xQ1   = (float*)carve((size_t)QN * 64 * 4);
  float* xq2p  = (float*)carve((size_t)QN * 64 * 4);
  float* sQ    = (float*)carve((size_t)SN * 64 * 4);
  float* sfp   = (float*)carve((size_t)SN * 64 * 4);
  float* c2pos = (float*)carve((size_t)QN * 4);
  float* c2neg = (float*)carve((size_t)QN * 4);
  int* beg_pos = (int*)carve((size_t)SN * 4);
  int* beg_neg = (int*)carve((size_t)SN * 4);
  int* cur_pos = (int*)carve((size_t)SN * 4);
  int* cur_neg = (int*)carve((size_t)SN * 4);
  int* csr_pos = (int*)carve((size_t)EN * 4);
  int* csr_neg = (int*)carve((size_t)EN * 4);
  if (off > ws_size) return;

  hipMemsetAsync(d_ws, 0, zero_bytes, stream);

  prep_kernel<<<4096 + 2 * (EN / 256), 256, 0, stream>>>(
      x, s_emb, W_Q, b_Q, W_K, b_K, W_V, b_V, W_fuse, b_fuse, W_K2, b_K2,
      h1b, h2b, es_pos, es_neg,
      xKpos, xKneg, xVfp, xQ1, xq2p, c2pos, c2neg, sQ, sfp,
      cnt_pos, cnt_neg);

  scan_kernel<<<dim3(1, 2), 256, 0, stream>>>(cnt_pos, beg_pos, cur_pos,
                                              cnt_neg, beg_neg, cur_neg);
  scatter_kernel<<<dim3(EN / 256, 2), 256, 0, stream>>>(es_pos, eq_pos, cur_pos, csr_pos,
                                                        es_neg, eq_neg, cur_neg, csr_neg, EN);

  main_kernel<<<dim3(SN, 2), 256, 0, stream>>>(
      xKpos, xKneg, xVfp, xQ1, xq2p, c2pos, c2neg, sQ, sfp,
      hq_pos, hc_pos, hq_neg, hc_neg,
      beg_pos, cnt_pos, csr_pos, beg_neg, cnt_neg, csr_neg,
      num_pos, den_pos, num_neg, den_neg);

  final_kernel<<<QN / 8, 256, 0, stream>>>(num_pos, den_pos, num_neg, den_neg,
                                           W_V2, b_V2, W_proj, b_proj, out);
}